// Round 8
// baseline (761.537 us; speedup 1.0000x reference)
//
#include <hip/hip_runtime.h>

static constexpr int MM  = 90000;  // cells
static constexpr int TT  = 150;    // steps
static constexpr int BS  = 256;    // threads per block (4 waves)
static constexpr int CPT = 16;     // cells per thread
static constexpr int CPB = BS * CPT;               // 4096 cells per block
static constexpr int NB  = (MM + CPB - 1) / CPB;   // 22 blocks (1 per CU, 1 wave/SIMD)
static constexpr int WPB = BS / 64;                // 4 waves
static constexpr int SLOTS = 64;                   // slot row: 22 real + 42 sentinel(=1u)

// Persistent device globals, re-initialized by init_ws_kernel EVERY launch.
// Cross-block traffic: relaxed agent-scope self-flagging words (no fences).
__device__ unsigned int g_bmax[TT + 1][SLOTS];     // per-block max s bits (s>0 => !=0)
__device__ __align__(64) unsigned long long g_edge[TT + 1][NB][2][2];  // [t][b][L/R][AQ,F]
__device__ unsigned long long g_dummy64;           // always nonzero (poll filler)

__device__ __forceinline__ float softplus_f(float x) {
    return fmaxf(x, 0.0f) + log1pf(expf(-fabsf(x)));
}
__device__ __forceinline__ unsigned long long packAQ(float A, float Q) {
    return ((unsigned long long)__float_as_uint(Q) << 32) | (unsigned long long)__float_as_uint(A);
}
#define AG_LOAD32(p)     __hip_atomic_load((p), __ATOMIC_RELAXED, __HIP_MEMORY_SCOPE_AGENT)
#define AG_LOAD64(p)     __hip_atomic_load((p), __ATOMIC_RELAXED, __HIP_MEMORY_SCOPE_AGENT)
#define AG_STORE32(p, v) __hip_atomic_store((p), (v), __ATOMIC_RELAXED, __HIP_MEMORY_SCOPE_AGENT)
#define AG_STORE64(p, v) __hip_atomic_store((p), (v), __ATOMIC_RELAXED, __HIP_MEMORY_SCOPE_AGENT)

__global__ void init_ws_kernel() {
    int i = blockIdx.x * blockDim.x + threadIdx.x;
    int stride = gridDim.x * blockDim.x;
    unsigned int* pb = &g_bmax[0][0];
    for (int j = i; j < (TT + 1) * SLOTS; j += stride)
        pb[j] = ((j & (SLOTS - 1)) < NB) ? 0u : 1u;   // sentinels "already arrived"
    unsigned long long* pe = &g_edge[0][0][0][0];
    for (int j = i; j < (TT + 1) * NB * 2 * 2; j += stride) pe[j] = 0ull;
    if (i == 0) g_dummy64 = ~0ull;
}

__global__ void __launch_bounds__(BS) sim_kernel(
    const float* __restrict__ Rs,
    const float* __restrict__ sim_dat,
    const float* __restrict__ sdc,
    const float* __restrict__ inflow,
    float* __restrict__ out)
{
    __shared__ float sE[2][WPB][2][3];   // [parity][wave][L/R edge cell][A,Q,F] (state_t)
    __shared__ float sred[2][WPB];       // [parity][wave] per-wave max s
    __shared__ float s_smaxv;            // final smax (ordered by post-barrier __syncthreads)
    __shared__ float s_hL[3], s_hR[3];   // remote halo (A,Q,F)
    __shared__ float s_inflow[TT];

    const int b    = blockIdx.x;
    const int tid  = threadIdx.x;
    const int wv   = tid >> 6;
    const int lane = tid & 63;
    const int base = b * CPB + tid * CPT;   // 16 contiguous cells per thread

    for (int j = tid; j < TT; j += BS) s_inflow[j] = inflow[j];

    // ---- per-cell constants & initial state (registers all sim) ----
    float A[CPT], Q[CPT], A0v[CPT], cbv[CPT], k2v[CPT], FQ[CPT];
    bool  act[CPT];
    float betMid = 1.0f, betEnd = 1.0f;
    int midSlot = -1, midCell = -1;
    #pragma unroll
    for (int c = 0; c < CPT; ++c) {
        int i = base + c;
        act[c] = (i < MM);
        float bt;
        if (act[c]) {
            A[c]   = fmaxf(sim_dat[i], 1e-6f);
            Q[c]   = 0.1f * sim_dat[MM + i];
            A0v[c] = sdc[i] + 0.5f;
            bt     = sdc[MM + i] + 1.0f;
        } else { A[c] = 1.0f; Q[c] = 0.0f; A0v[c] = 1.0f; bt = 1.0f; }
        cbv[c] = (0.5f * bt) / 1060.0f;     // (0.5*beta)/RHO  (ref op order)
        k2v[c] = bt / (3180.0f * A0v[c]);   // beta/(3*RHO*A0)
        if (i == 15000) { midSlot = 0; midCell = c; betMid = bt; }
        else if (i == 45000) { midSlot = 1; midCell = c; betMid = bt; }
        else if (i == 75000) { midSlot = 2; midCell = c; betMid = bt; }
        if (c == CPT - 1) betEnd = bt;
    }
    const bool isStart = (base == 0) | (base == 30000) | (base == 60000);   // cell 0 (all ≡0 mod 16)
    const int  iLast   = base + CPT - 1;
    const bool isEnd   = (iLast == 29999) | (iLast == 59999) | (iLast == 89999);  // cell 15
    float Rtot = 1.0f;
    if (isEnd) {
        float R1 = sdc[7 * MM + iLast] + 0.5f;
        float R2 = sdc[8 * MM + iLast] + 0.5f;
        if (iLast == 59999)      { R1 *= softplus_f(Rs[0]); R2 *= softplus_f(Rs[1]); }
        else if (iLast == 89999) { R1 *= softplus_f(Rs[2]); R2 *= softplus_f(Rs[3]); }
        Rtot = R1 + R2;
    }

    const bool pubL = (tid == 0) && (b > 0);            // publish my left edge (read by b-1)
    const bool pubR = (tid == BS - 1) && (b < NB - 1);  // publish my right edge (read by b+1)
    const bool fixL = pubL;                             // my cell0 uses remote left halo
    const bool fixR = pubR;                             // my cell15 uses remote right halo

    // ---- initial derived state + t=0 publishes ----
    float s16 = 0.0f, sqMid = 1.0f, sqEnd = 1.0f;
    #pragma unroll
    for (int c = 0; c < CPT; ++c) {
        float sqc = sqrtf(A[c] / A0v[c]);
        float u   = Q[c] / A[c];
        float cc  = sqrtf(cbv[c] * sqc);
        FQ[c] = Q[c] * u + k2v[c] * A[c] * sqc;
        s16 = fmaxf(s16, act[c] ? (fabsf(u) + cc) : 0.0f);
        if (c == midCell) sqMid = sqc;
        if (c == CPT - 1) sqEnd = sqc;
    }
    if (pubL) {
        AG_STORE64(&g_edge[0][b][0][0], packAQ(A[0], Q[0]));
        AG_STORE64(&g_edge[0][b][0][1], (unsigned long long)__float_as_uint(FQ[0]));
    }
    if (pubR) {
        AG_STORE64(&g_edge[0][b][1][0], packAQ(A[CPT-1], Q[CPT-1]));
        AG_STORE64(&g_edge[0][b][1][1], (unsigned long long)__float_as_uint(FQ[CPT-1]));
    }
    {
        float mm = s16;
        #pragma unroll
        for (int off = 32; off > 0; off >>= 1) mm = fmaxf(mm, __shfl_xor(mm, off, 64));
        if (lane == 0)       { sE[0][wv][0][0] = A[0]; sE[0][wv][0][1] = Q[0]; sE[0][wv][0][2] = FQ[0];
                               sred[0][wv] = mm; }
        else if (lane == 63) { sE[0][wv][1][0] = A[CPT-1]; sE[0][wv][1][1] = Q[CPT-1]; sE[0][wv][1][2] = FQ[CPT-1]; }
    }
    __syncthreads();
    if (wv == 0 && lane == 0) {
        float bm = fmaxf(fmaxf(sred[0][0], sred[0][1]), fmaxf(sred[0][2], sred[0][3]));
        AG_STORE32(&g_bmax[0][b], __float_as_uint(bm));
    }

    for (int t = 0; t < TT; ++t) {
        const int par = t & 1, npar = par ^ 1;

        // ===== pre-barrier: neighbor exchange + smax-independent stencil terms =====
        float Am = __shfl_up(A[CPT-1], 1, 64),  Qm = __shfl_up(Q[CPT-1], 1, 64),  Fm = __shfl_up(FQ[CPT-1], 1, 64);
        float Ap = __shfl_down(A[0], 1, 64), Qp = __shfl_down(Q[0], 1, 64), Fp = __shfl_down(FQ[0], 1, 64);
        if (lane == 0 && wv > 0)       { Am = sE[par][wv-1][1][0]; Qm = sE[par][wv-1][1][1]; Fm = sE[par][wv-1][1][2]; }
        if (lane == 63 && wv < WPB - 1){ Ap = sE[par][wv+1][0][0]; Qp = sE[par][wv+1][0][1]; Fp = sE[par][wv+1][0][2]; }

        float dFA[CPT], lapA[CPT], dFQ[CPT], lapQ[CPT];
        #pragma unroll
        for (int c = 0; c < CPT; ++c) {
            float Al = (c == 0) ? Am : A[c-1],        Ql = (c == 0) ? Qm : Q[c-1],        Fl = (c == 0) ? Fm : FQ[c-1];
            float Ar = (c == CPT-1) ? Ap : A[c+1],    Qr = (c == CPT-1) ? Qp : Q[c+1],    Fr = (c == CPT-1) ? Fp : FQ[c+1];
            dFA[c]  = 0.5f * (Qr - Ql);
            lapA[c] = 0.5f * (Ar - 2.0f * A[c] + Al);
            dFQ[c]  = 0.5f * (Fr - Fl);
            lapQ[c] = 0.5f * (Qr - 2.0f * Q[c] + Ql);
        }
        if (midSlot >= 0) out[t * 3 + midSlot] = betMid * (sqMid - 1.0f);
        const float Pend = betEnd * (sqEnd - 1.0f);   // used only by isEnd threads

        // ===== flat single-hop barrier: wave 0 polls the whole slot row =====
        if (wv == 0) {
            // lanes 0-3 additionally poll the block's halo words (dummy if absent)
            const unsigned long long* pE = &g_dummy64;
            if (lane == 0 && b > 0)           pE = &g_edge[t][b - 1][1][0];
            else if (lane == 1 && b > 0)      pE = &g_edge[t][b - 1][1][1];
            else if (lane == 2 && b < NB - 1) pE = &g_edge[t][b + 1][0][0];
            else if (lane == 3 && b < NB - 1) pE = &g_edge[t][b + 1][0][1];
            const unsigned int* row = &g_bmax[t][0];
            unsigned int x;
            unsigned long long e64;
            for (;;) {
                x   = AG_LOAD32(row + lane);   // 64 words = 4 lines, 22 real slots
                e64 = AG_LOAD64(pE);
                if (__all((x != 0u) & (e64 != 0ull))) break;
            }
            float ml = __uint_as_float(x);     // sentinels are denormal -> ignored by max
            #pragma unroll
            for (int off = 32; off > 0; off >>= 1) ml = fmaxf(ml, __shfl_xor(ml, off, 64));
            if (lane == 0) s_smaxv = ml;
            if (lane == 0 && b > 0)           { s_hL[0] = __uint_as_float((unsigned int)e64);
                                                s_hL[1] = __uint_as_float((unsigned int)(e64 >> 32)); }
            else if (lane == 1 && b > 0)      { s_hL[2] = __uint_as_float((unsigned int)e64); }
            else if (lane == 2 && b < NB - 1) { s_hR[0] = __uint_as_float((unsigned int)e64);
                                                s_hR[1] = __uint_as_float((unsigned int)(e64 >> 32)); }
            else if (lane == 3 && b < NB - 1) { s_hR[2] = __uint_as_float((unsigned int)e64); }
        }
        __syncthreads();

        // ===== post-barrier: smax-dependent tail =====
        const float smax = s_smaxv;
        const float dt  = ((float)(0.9 * 0.001)) / smax;   // ref op order
        const float lam = dt / 0.001f;
        const float w   = lam * smax;

        if (fixL) {   // cell 0 stencil terms from remote halo
            float Al = s_hL[0], Ql = s_hL[1], Fl = s_hL[2];
            dFA[0]  = 0.5f * (Q[1] - Ql);
            lapA[0] = 0.5f * (A[1] - 2.0f * A[0] + Al);
            dFQ[0]  = 0.5f * (FQ[1] - Fl);
            lapQ[0] = 0.5f * (Q[1] - 2.0f * Q[0] + Ql);
        }
        if (fixR) {   // cell 15 stencil terms from remote halo
            float Ar = s_hR[0], Qr = s_hR[1], Fr = s_hR[2];
            dFA[CPT-1]  = 0.5f * (Qr - Q[CPT-2]);
            lapA[CPT-1] = 0.5f * (Ar - 2.0f * A[CPT-1] + A[CPT-2]);
            dFQ[CPT-1]  = 0.5f * (Fr - FQ[CPT-2]);
            lapQ[CPT-1] = 0.5f * (Qr - 2.0f * Q[CPT-1] + Q[CPT-2]);
        }
        #pragma unroll
        for (int c = 0; c < CPT; ++c) {
            int i = base + c;
            if (act[c] && i > 0 && i < MM - 1) {
                A[c] = fmaf(w, lapA[c], fmaf(-lam, dFA[c], A[c]));
                Q[c] = fmaf(w, lapQ[c], fmaf(-lam, dFQ[c], Q[c]));
            }
        }
        if (isStart) Q[0] = s_inflow[t];
        if (isEnd)   Q[CPT-1] = Pend / Rtot;
        #pragma unroll
        for (int c = 0; c < CPT; ++c) A[c] = fmaxf(A[c], 1e-6f);

        // publish t+1 edge AQ ASAP (F follows after derived recompute)
        if (pubL) AG_STORE64(&g_edge[t+1][b][0][0], packAQ(A[0], Q[0]));
        if (pubR) AG_STORE64(&g_edge[t+1][b][1][0], packAQ(A[CPT-1], Q[CPT-1]));

        // derived state for t+1 + wave max
        s16 = 0.0f;
        #pragma unroll
        for (int c = 0; c < CPT; ++c) {
            float sqc = sqrtf(A[c] / A0v[c]);
            float u   = Q[c] / A[c];
            float cc  = sqrtf(cbv[c] * sqc);
            FQ[c] = Q[c] * u + k2v[c] * A[c] * sqc;
            s16 = fmaxf(s16, act[c] ? (fabsf(u) + cc) : 0.0f);
            if (c == midCell) sqMid = sqc;
            if (c == CPT - 1) sqEnd = sqc;
        }
        if (pubL) AG_STORE64(&g_edge[t+1][b][0][1], (unsigned long long)__float_as_uint(FQ[0]));
        if (pubR) AG_STORE64(&g_edge[t+1][b][1][1], (unsigned long long)__float_as_uint(FQ[CPT-1]));

        float mm = s16;
        #pragma unroll
        for (int off = 32; off > 0; off >>= 1) mm = fmaxf(mm, __shfl_xor(mm, off, 64));
        if (lane == 0)       { sE[npar][wv][0][0] = A[0]; sE[npar][wv][0][1] = Q[0]; sE[npar][wv][0][2] = FQ[0];
                               sred[npar][wv] = mm; }
        else if (lane == 63) { sE[npar][wv][1][0] = A[CPT-1]; sE[npar][wv][1][1] = Q[CPT-1]; sE[npar][wv][1][2] = FQ[CPT-1]; }
        __syncthreads();

        if (wv == 0 && lane == 0) {
            float bm = fmaxf(fmaxf(sred[npar][0], sred[npar][1]), fmaxf(sred[npar][2], sred[npar][3]));
            AG_STORE32(&g_bmax[t + 1][b], __float_as_uint(bm));
        }
    }
}

extern "C" void kernel_launch(void* const* d_in, const int* in_sizes, int n_in,
                              void* d_out, int out_size, void* d_ws, size_t ws_size,
                              hipStream_t stream) {
    (void)in_sizes; (void)n_in; (void)d_ws; (void)ws_size; (void)out_size;

    const float* Rs      = (const float*)d_in[0];
    const float* sim_dat = (const float*)d_in[1];
    const float* sdc     = (const float*)d_in[2];
    const float* inflow  = (const float*)d_in[3];
    float* out = (float*)d_out;

    hipLaunchKernelGGL(init_ws_kernel, dim3(120), dim3(256), 0, stream);

    // 22 blocks x 4 waves: 1 block/CU, 1 wave/SIMD -> VGPR budget 512, no occupancy bind.
    hipLaunchKernelGGL(sim_kernel, dim3(NB), dim3(BS), 0, stream,
                       Rs, sim_dat, sdc, inflow, out);
}

// Round 9
// 480.928 us; speedup vs baseline: 1.5835x; 1.5835x over previous
//
#include <hip/hip_runtime.h>

static constexpr int MM  = 90000;  // cells
static constexpr int TT  = 150;    // steps
static constexpr int BS  = 256;    // threads per block (4 waves)
static constexpr int CPT = 4;      // cells per thread
static constexpr int CPB = BS * CPT;               // 1024 cells per block
static constexpr int NB  = (MM + CPB - 1) / CPB;   // 88 blocks
static constexpr int WPB = BS / 64;                // 4 waves
static constexpr int PAGE_U32 = 2048;              // 8 KB page per block -> own channel
static constexpr int PAGE_U64 = 1024;              // 8 KB page per block

// Persistent device globals, re-initialized by init_ws_kernel EVERY launch.
// Channel-spread layout: each block's flag/halo words live in their OWN 8KB
// page so the per-step publish burst is not serialized on one memory channel.
__device__ unsigned int       g_bmax_s[128][PAGE_U32];   // [page][t]; pages NB..127 preset 1u
__device__ unsigned long long g_edge_s[NB][PAGE_U64];    // [b][t*4 + side*2 + {AQ,F}]
__device__ unsigned long long g_dummy64;                 // always nonzero (boundary filler)

__device__ __forceinline__ float softplus_f(float x) {
    return fmaxf(x, 0.0f) + log1pf(expf(-fabsf(x)));
}
__device__ __forceinline__ unsigned long long packAQ(float A, float Q) {
    return ((unsigned long long)__float_as_uint(Q) << 32) | (unsigned long long)__float_as_uint(A);
}
#define AG_LOAD32(p)     __hip_atomic_load((p), __ATOMIC_RELAXED, __HIP_MEMORY_SCOPE_AGENT)
#define AG_LOAD64(p)     __hip_atomic_load((p), __ATOMIC_RELAXED, __HIP_MEMORY_SCOPE_AGENT)
#define AG_STORE32(p, v) __hip_atomic_store((p), (v), __ATOMIC_RELAXED, __HIP_MEMORY_SCOPE_AGENT)
#define AG_STORE64(p, v) __hip_atomic_store((p), (v), __ATOMIC_RELAXED, __HIP_MEMORY_SCOPE_AGENT)

__global__ void init_ws_kernel() {
    int i = blockIdx.x * blockDim.x + threadIdx.x;
    int stride = gridDim.x * blockDim.x;
    unsigned int* pb = &g_bmax_s[0][0];
    for (int j = i; j < 128 * PAGE_U32; j += stride)
        pb[j] = ((j / PAGE_U32) < NB) ? 0u : 1u;   // sentinel pages "already arrived"
    unsigned long long* pe = &g_edge_s[0][0];
    for (int j = i; j < NB * PAGE_U64; j += stride) pe[j] = 0ull;
    if (i == 0) g_dummy64 = ~0ull;
}

__global__ void __launch_bounds__(BS) sim_kernel(
    const float* __restrict__ Rs,
    const float* __restrict__ sim_dat,
    const float* __restrict__ sdc,
    const float* __restrict__ inflow,
    float* __restrict__ out)
{
    __shared__ float sE[2][WPB][2][3];   // [parity][wave][L/R edge cell][A,Q,F] (state_t)
    __shared__ float sred[2][WPB];       // [parity][wave] per-wave max s
    __shared__ float s_smaxv;            // final smax (ordered by post-barrier __syncthreads)
    __shared__ float s_hL[3], s_hR[3];   // remote halo (A,Q,F)
    __shared__ float s_inflow[TT];

    const int b    = blockIdx.x;
    const int tid  = threadIdx.x;
    const int wv   = tid >> 6;
    const int lane = tid & 63;
    const int base = b * CPB + tid * CPT;   // 4 contiguous cells per thread

    for (int j = tid; j < TT; j += BS) s_inflow[j] = inflow[j];

    // ---- per-cell constants & initial state (registers all sim) ----
    float A[CPT], Q[CPT], A0v[CPT], bet[CPT], cbv[CPT], k2v[CPT], sq[CPT], FQ[CPT];
    bool  act[CPT];
    #pragma unroll
    for (int c = 0; c < CPT; ++c) {
        int i = base + c;
        act[c] = (i < MM);
        if (act[c]) {
            A[c]   = fmaxf(sim_dat[i], 1e-6f);
            Q[c]   = 0.1f * sim_dat[MM + i];
            A0v[c] = sdc[i] + 0.5f;
            bet[c] = sdc[MM + i] + 1.0f;
        } else { A[c] = 1.0f; Q[c] = 0.0f; A0v[c] = 1.0f; bet[c] = 1.0f; }
        cbv[c] = (0.5f * bet[c]) / 1060.0f;     // (0.5*beta)/RHO  (ref op order)
        k2v[c] = bet[c] / (3180.0f * A0v[c]);   // beta/(3*RHO*A0)
    }
    const bool isStart = (base == 0) | (base == 30000) | (base == 60000);                  // cell 0
    const bool isEnd   = (base + 3 == 29999) | (base + 3 == 59999) | (base + 3 == 89999);  // cell 3
    const int midSlot = (base == 15000) ? 0 : (base == 45000) ? 1 : (base == 75000) ? 2 : -1;
    float Rtot = 1.0f;
    if (isEnd) {
        int i3 = base + 3;
        float R1 = sdc[7 * MM + i3] + 0.5f;
        float R2 = sdc[8 * MM + i3] + 0.5f;
        if (i3 == 59999)      { R1 *= softplus_f(Rs[0]); R2 *= softplus_f(Rs[1]); }
        else if (i3 == 89999) { R1 *= softplus_f(Rs[2]); R2 *= softplus_f(Rs[3]); }
        Rtot = R1 + R2;
    }

    const bool pubL = (tid == 0) && (b > 0);            // publish my left edge (read by b-1)
    const bool pubR = (tid == BS - 1) && (b < NB - 1);  // publish my right edge (read by b+1)
    const bool fixL = pubL;                             // my cell0 uses remote left halo
    const bool fixR = pubR;                             // my cell3 uses remote right halo

    // ---- initial derived state + t=0 publishes ----
    float s4 = 0.0f;
    #pragma unroll
    for (int c = 0; c < CPT; ++c) {
        sq[c] = sqrtf(A[c] / A0v[c]);
        float u  = Q[c] / A[c];
        float cc = sqrtf(cbv[c] * sq[c]);
        FQ[c] = Q[c] * u + k2v[c] * A[c] * sq[c];
        s4 = fmaxf(s4, act[c] ? (fabsf(u) + cc) : 0.0f);
    }
    if (pubL) {   // my L-edge words: [b][t*4+0]=AQ, [b][t*4+1]=F
        AG_STORE64(&g_edge_s[b][0], packAQ(A[0], Q[0]));
        AG_STORE64(&g_edge_s[b][1], (unsigned long long)__float_as_uint(FQ[0]));
    }
    if (pubR) {   // my R-edge words: [b][t*4+2]=AQ, [b][t*4+3]=F
        AG_STORE64(&g_edge_s[b][2], packAQ(A[3], Q[3]));
        AG_STORE64(&g_edge_s[b][3], (unsigned long long)__float_as_uint(FQ[3]));
    }
    {
        float mm = s4;
        #pragma unroll
        for (int off = 32; off > 0; off >>= 1) mm = fmaxf(mm, __shfl_xor(mm, off, 64));
        if (lane == 0)       { sE[0][wv][0][0] = A[0]; sE[0][wv][0][1] = Q[0]; sE[0][wv][0][2] = FQ[0];
                               sred[0][wv] = mm; }
        else if (lane == 63) { sE[0][wv][1][0] = A[3]; sE[0][wv][1][1] = Q[3]; sE[0][wv][1][2] = FQ[3]; }
    }
    __syncthreads();
    if (wv == 0 && lane == 0) {
        float bm = fmaxf(fmaxf(sred[0][0], sred[0][1]), fmaxf(sred[0][2], sred[0][3]));
        AG_STORE32(&g_bmax_s[b][0], __float_as_uint(bm));
    }

    for (int t = 0; t < TT; ++t) {
        const int par = t & 1, npar = par ^ 1;

        // ===== pre-barrier: neighbor exchange + smax-independent stencil terms =====
        float Am = __shfl_up(A[3], 1, 64),  Qm = __shfl_up(Q[3], 1, 64),  Fm = __shfl_up(FQ[3], 1, 64);
        float Ap = __shfl_down(A[0], 1, 64), Qp = __shfl_down(Q[0], 1, 64), Fp = __shfl_down(FQ[0], 1, 64);
        if (lane == 0 && wv > 0)       { Am = sE[par][wv-1][1][0]; Qm = sE[par][wv-1][1][1]; Fm = sE[par][wv-1][1][2]; }
        if (lane == 63 && wv < WPB - 1){ Ap = sE[par][wv+1][0][0]; Qp = sE[par][wv+1][0][1]; Fp = sE[par][wv+1][0][2]; }

        float dFA[CPT], lapA[CPT], dFQ[CPT], lapQ[CPT];
        #pragma unroll
        for (int c = 0; c < CPT; ++c) {
            float Al = (c == 0) ? Am : A[c-1],  Ql = (c == 0) ? Qm : Q[c-1],  Fl = (c == 0) ? Fm : FQ[c-1];
            float Ar = (c == 3) ? Ap : A[c+1],  Qr = (c == 3) ? Qp : Q[c+1],  Fr = (c == 3) ? Fp : FQ[c+1];
            dFA[c]  = 0.5f * (Qr - Ql);
            lapA[c] = 0.5f * (Ar - 2.0f * A[c] + Al);
            dFQ[c]  = 0.5f * (Fr - Fl);
            lapQ[c] = 0.5f * (Qr - 2.0f * Q[c] + Ql);
        }
        if (midSlot >= 0) out[t * 3 + midSlot] = bet[0] * (sq[0] - 1.0f);
        const float Pend = bet[3] * (sq[3] - 1.0f);   // used only by isEnd threads

        // ===== flat barrier: wave 0 gathers one word per channel-spread page =====
        if (wv == 0) {
            // lanes 0-3 additionally poll the block's halo words (dummy if absent)
            const unsigned long long* pE = &g_dummy64;
            const int t4 = t * 4;
            if (lane == 0 && b > 0)           pE = &g_edge_s[b - 1][t4 + 2];  // left nbr R-AQ
            else if (lane == 1 && b > 0)      pE = &g_edge_s[b - 1][t4 + 3];  // left nbr R-F
            else if (lane == 2 && b < NB - 1) pE = &g_edge_s[b + 1][t4 + 0];  // right nbr L-AQ
            else if (lane == 3 && b < NB - 1) pE = &g_edge_s[b + 1][t4 + 1];  // right nbr L-F
            unsigned int x0, x1;
            unsigned long long e64;
            for (;;) {
                x0  = AG_LOAD32(&g_bmax_s[lane][t]);        // 64 pages, 64 channels, parallel
                x1  = AG_LOAD32(&g_bmax_s[64 + lane][t]);   // pages 64..127 (88+ = sentinel 1u)
                e64 = AG_LOAD64(pE);
                if (__all((x0 != 0u) & (x1 != 0u) & (e64 != 0ull))) break;
            }
            float ml = fmaxf(__uint_as_float(x0), __uint_as_float(x1));  // sentinels ~1e-45
            #pragma unroll
            for (int off = 32; off > 0; off >>= 1) ml = fmaxf(ml, __shfl_xor(ml, off, 64));
            if (lane == 0) s_smaxv = ml;
            if (lane == 0 && b > 0)           { s_hL[0] = __uint_as_float((unsigned int)e64);
                                                s_hL[1] = __uint_as_float((unsigned int)(e64 >> 32)); }
            else if (lane == 1 && b > 0)      { s_hL[2] = __uint_as_float((unsigned int)e64); }
            else if (lane == 2 && b < NB - 1) { s_hR[0] = __uint_as_float((unsigned int)e64);
                                                s_hR[1] = __uint_as_float((unsigned int)(e64 >> 32)); }
            else if (lane == 3 && b < NB - 1) { s_hR[2] = __uint_as_float((unsigned int)e64); }
        }
        __syncthreads();

        // ===== post-barrier: smax-dependent tail =====
        const float smax = s_smaxv;
        const float dt  = ((float)(0.9 * 0.001)) / smax;   // ref op order
        const float lam = dt / 0.001f;
        const float w   = lam * smax;

        if (fixL) {   // cell 0 stencil terms from remote halo
            float Al = s_hL[0], Ql = s_hL[1], Fl = s_hL[2];
            dFA[0]  = 0.5f * (Q[1] - Ql);
            lapA[0] = 0.5f * (A[1] - 2.0f * A[0] + Al);
            dFQ[0]  = 0.5f * (FQ[1] - Fl);
            lapQ[0] = 0.5f * (Q[1] - 2.0f * Q[0] + Ql);
        }
        if (fixR) {   // cell 3 stencil terms from remote halo
            float Ar = s_hR[0], Qr = s_hR[1], Fr = s_hR[2];
            dFA[3]  = 0.5f * (Qr - Q[2]);
            lapA[3] = 0.5f * (Ar - 2.0f * A[3] + A[2]);
            dFQ[3]  = 0.5f * (Fr - FQ[2]);
            lapQ[3] = 0.5f * (Qr - 2.0f * Q[3] + Q[2]);
        }
        #pragma unroll
        for (int c = 0; c < CPT; ++c) {
            int i = base + c;
            if (act[c] && i > 0 && i < MM - 1) {
                A[c] = fmaf(w, lapA[c], fmaf(-lam, dFA[c], A[c]));
                Q[c] = fmaf(w, lapQ[c], fmaf(-lam, dFQ[c], Q[c]));
            }
        }
        if (isStart) Q[0] = s_inflow[t];
        if (isEnd)   Q[3] = Pend / Rtot;
        #pragma unroll
        for (int c = 0; c < CPT; ++c) A[c] = fmaxf(A[c], 1e-6f);

        // publish t+1 edge AQ ASAP (F follows after derived recompute)
        const int n4 = (t + 1) * 4;
        if (pubL) AG_STORE64(&g_edge_s[b][n4 + 0], packAQ(A[0], Q[0]));
        if (pubR) AG_STORE64(&g_edge_s[b][n4 + 2], packAQ(A[3], Q[3]));

        // derived state for t+1 + wave max
        s4 = 0.0f;
        #pragma unroll
        for (int c = 0; c < CPT; ++c) {
            sq[c] = sqrtf(A[c] / A0v[c]);
            float u  = Q[c] / A[c];
            float cc = sqrtf(cbv[c] * sq[c]);
            FQ[c] = Q[c] * u + k2v[c] * A[c] * sq[c];
            s4 = fmaxf(s4, act[c] ? (fabsf(u) + cc) : 0.0f);
        }
        if (pubL) AG_STORE64(&g_edge_s[b][n4 + 1], (unsigned long long)__float_as_uint(FQ[0]));
        if (pubR) AG_STORE64(&g_edge_s[b][n4 + 3], (unsigned long long)__float_as_uint(FQ[3]));

        float mm = s4;
        #pragma unroll
        for (int off = 32; off > 0; off >>= 1) mm = fmaxf(mm, __shfl_xor(mm, off, 64));
        if (lane == 0)       { sE[npar][wv][0][0] = A[0]; sE[npar][wv][0][1] = Q[0]; sE[npar][wv][0][2] = FQ[0];
                               sred[npar][wv] = mm; }
        else if (lane == 63) { sE[npar][wv][1][0] = A[3]; sE[npar][wv][1][1] = Q[3]; sE[npar][wv][1][2] = FQ[3]; }
        __syncthreads();

        if (wv == 0 && lane == 0) {
            float bm = fmaxf(fmaxf(sred[npar][0], sred[npar][1]), fmaxf(sred[npar][2], sred[npar][3]));
            AG_STORE32(&g_bmax_s[b][t + 1], __float_as_uint(bm));
        }
    }
}

extern "C" void kernel_launch(void* const* d_in, const int* in_sizes, int n_in,
                              void* d_out, int out_size, void* d_ws, size_t ws_size,
                              hipStream_t stream) {
    (void)in_sizes; (void)n_in; (void)d_ws; (void)ws_size; (void)out_size;

    const float* Rs      = (const float*)d_in[0];
    const float* sim_dat = (const float*)d_in[1];
    const float* sdc     = (const float*)d_in[2];
    const float* inflow  = (const float*)d_in[3];
    float* out = (float*)d_out;

    hipLaunchKernelGGL(init_ws_kernel, dim3(240), dim3(256), 0, stream);

    // 88 blocks x 4 waves, ~2 KB LDS -> trivially co-resident on 256 CUs.
    hipLaunchKernelGGL(sim_kernel, dim3(NB), dim3(BS), 0, stream,
                       Rs, sim_dat, sdc, inflow, out);
}